// Round 5
// baseline (26.066 us; speedup 1.0000x reference)
//
#include <hip/hip_runtime.h>

// Problem constants: pred [1,4,2048,2048] fp32, true [2048,2048] int32 (labels 0..3)
static constexpr int HW   = 2048 * 2048;   // pixels
static constexpr int NQ   = HW / 4;        // float4 / int4 quads
static constexpr int NBLK = 2048;
static constexpr int NTHR = 256;
static constexpr int QPT  = NQ / (NBLK * NTHR);  // = 2 quads (8 pixels) per thread
static constexpr int FTHR = 1024;                // finalize threads

// d_ws layout (SoA planes, each NBLK uint4, 32 KB apart):
//   planeP[NBLK]: per-block p_sum  (argmax==c) for classes 0..3
//   planeT[NBLK]: per-block t_sum  (true==c)
//   planeI[NBLK]: per-block inter  (argmax==c && true==c)

__global__ __launch_bounds__(NTHR) void count_kernel(const float* __restrict__ pred,
                                                     const int* __restrict__ lbl,
                                                     uint4* __restrict__ planeP,
                                                     uint4* __restrict__ planeT,
                                                     uint4* __restrict__ planeI) {
    const float4* __restrict__ p0 = (const float4*)(pred);
    const float4* __restrict__ p1 = (const float4*)(pred + (size_t)HW);
    const float4* __restrict__ p2 = (const float4*)(pred + (size_t)2 * HW);
    const float4* __restrict__ p3 = (const float4*)(pred + (size_t)3 * HW);
    const int4*   __restrict__ tl = (const int4*)(lbl);

    // byte-packed per-thread counters: 8-bit lane per class (max 8 pixels/thread)
    unsigned int pc = 0u, tc = 0u, ic = 0u;

    const int base = blockIdx.x * NTHR + threadIdx.x;
#pragma unroll
    for (int q = 0; q < QPT; ++q) {
        const int i = base + q * (NBLK * NTHR);
        float4 a = p0[i];
        float4 b = p1[i];
        float4 c = p2[i];
        float4 d = p3[i];
        int4   t = tl[i];

        float a_[4] = {a.x, a.y, a.z, a.w};
        float b_[4] = {b.x, b.y, b.z, b.w};
        float c_[4] = {c.x, c.y, c.z, c.w};
        float d_[4] = {d.x, d.y, d.z, d.w};
        int   t_[4] = {t.x, t.y, t.z, t.w};

#pragma unroll
        for (int j = 0; j < 4; ++j) {
            // jnp.argmax tie-break: first (lowest) index among maxima -> strict '>'
            float best = a_[j];
            int   pi   = 0;
            if (b_[j] > best) { best = b_[j]; pi = 1; }
            if (c_[j] > best) { best = c_[j]; pi = 2; }
            if (d_[j] > best) { best = d_[j]; pi = 3; }
            int tj = t_[j];
            pc += 1u << (pi * 8);
            tc += 1u << (tj * 8);
            ic += (pi == tj) ? (1u << (pi * 8)) : 0u;
        }
    }

    // widen 8-bit lanes -> two u32 with 16-bit lanes (classes {0,2} in lo, {1,3} in hi)
    unsigned int plo = pc & 0x00FF00FFu, phi = (pc >> 8) & 0x00FF00FFu;
    unsigned int tlo = tc & 0x00FF00FFu, thi = (tc >> 8) & 0x00FF00FFu;
    unsigned int ilo = ic & 0x00FF00FFu, ihi = (ic >> 8) & 0x00FF00FFu;

    // wave-64 reduction (16-bit lanes: max 64*8=512 per lane, no overflow)
#pragma unroll
    for (int off = 32; off > 0; off >>= 1) {
        plo += __shfl_down(plo, off);
        phi += __shfl_down(phi, off);
        tlo += __shfl_down(tlo, off);
        thi += __shfl_down(thi, off);
        ilo += __shfl_down(ilo, off);
        ihi += __shfl_down(ihi, off);
    }

    __shared__ unsigned int red[NTHR / 64][6];
    int wave = threadIdx.x >> 6;
    int lane = threadIdx.x & 63;
    if (lane == 0) {
        red[wave][0] = plo; red[wave][1] = phi;
        red[wave][2] = tlo; red[wave][3] = thi;
        red[wave][4] = ilo; red[wave][5] = ihi;
    }
    __syncthreads();

    if (threadIdx.x == 0) {
        unsigned int s[6];
#pragma unroll
        for (int k = 0; k < 6; ++k) {
            unsigned int acc = 0;
#pragma unroll
            for (int w = 0; w < NTHR / 64; ++w) acc += red[w][k];
            s[k] = acc;  // 16-bit lanes: max 4*512 = 2048, no overflow
        }
        // lo16 = class{0 or 1}, hi16 = class{2 or 3}
        planeP[blockIdx.x] = make_uint4(s[0] & 0xFFFFu, s[1] & 0xFFFFu, s[0] >> 16, s[1] >> 16);
        planeT[blockIdx.x] = make_uint4(s[2] & 0xFFFFu, s[3] & 0xFFFFu, s[2] >> 16, s[3] >> 16);
        planeI[blockIdx.x] = make_uint4(s[4] & 0xFFFFu, s[5] & 0xFFFFu, s[4] >> 16, s[5] >> 16);
    }
}

__global__ __launch_bounds__(FTHR) void finalize_kernel(const uint4* __restrict__ planeP,
                                                        const uint4* __restrict__ planeT,
                                                        const uint4* __restrict__ planeI,
                                                        float* __restrict__ out) {
    unsigned int s[12];
#pragma unroll
    for (int k = 0; k < 12; ++k) s[k] = 0u;

    // coalesced SoA reads: consecutive lanes read consecutive uint4 in each plane
#pragma unroll
    for (int q = 0; q < NBLK / FTHR; ++q) {
        const int b = threadIdx.x + q * FTHR;
        uint4 r0 = planeP[b], r1 = planeT[b], r2 = planeI[b];
        s[0] += r0.x; s[1] += r0.y; s[2]  += r0.z; s[3]  += r0.w;
        s[4] += r1.x; s[5] += r1.y; s[6]  += r1.z; s[7]  += r1.w;
        s[8] += r2.x; s[9] += r2.y; s[10] += r2.z; s[11] += r2.w;
    }

    // wave reduce each of the 12 sums
#pragma unroll
    for (int off = 32; off > 0; off >>= 1) {
#pragma unroll
        for (int k = 0; k < 12; ++k) s[k] += __shfl_down(s[k], off);
    }

    __shared__ unsigned int red[FTHR / 64][12];
    int wave = threadIdx.x >> 6;
    int lane = threadIdx.x & 63;
    if (lane == 0) {
#pragma unroll
        for (int k = 0; k < 12; ++k) red[wave][k] = s[k];
    }
    __syncthreads();

    if (threadIdx.x == 0) {
        unsigned int tot[12];
#pragma unroll
        for (int k = 0; k < 12; ++k) {
            unsigned int acc = 0;
#pragma unroll
            for (int w = 0; w < FTHR / 64; ++w) acc += red[w][k];
            tot[k] = acc;
        }
        float p[4], t[4], in[4];
        float sp = 0.f, st = 0.f;
#pragma unroll
        for (int c = 0; c < 4; ++c) {
            p[c]  = (float)tot[c];
            t[c]  = (float)tot[4 + c];
            in[c] = (float)tot[8 + c];
            sp += p[c];
            st += t[c];
        }
        const float S = 1e-5f;
        float total = sp + st;  // == p1h.sum() + t1h.sum()
        float dsum = 0.f, isum = 0.f;
        int npres = 0;
#pragma unroll
        for (int c = 0; c < 4; ++c) {
            if (tot[4 + c] > 0u) {  // class present in `true`
                ++npres;
                dsum += 1.0f - (2.0f * in[c] + S) / (p[c] + t[c] + S);
                isum += 1.0f - (in[c] + S) / (total + S - in[c]);
            }
        }
        float n = (float)(npres > 0 ? npres : 1);
        out[0] = dsum / n + isum / n;
    }
}

extern "C" void kernel_launch(void* const* d_in, const int* in_sizes, int n_in,
                              void* d_out, int out_size, void* d_ws, size_t ws_size,
                              hipStream_t stream) {
    const float* pred = (const float*)d_in[0];
    const int*   lbl  = (const int*)d_in[1];
    float*       out  = (float*)d_out;
    uint4* planeP = (uint4*)d_ws;            // NBLK uint4 = 32 KB
    uint4* planeT = planeP + NBLK;           // 32 KB
    uint4* planeI = planeT + NBLK;           // 32 KB

    count_kernel<<<NBLK, NTHR, 0, stream>>>(pred, lbl, planeP, planeT, planeI);
    finalize_kernel<<<1, FTHR, 0, stream>>>(planeP, planeT, planeI, out);
}

// Round 6
// 23.974 us; speedup vs baseline: 1.0873x; 1.0873x over previous
//
#include <hip/hip_runtime.h>

// Problem constants: pred [1,4,2048,2048] fp32, true [2048,2048] int32 (labels 0..3)
static constexpr int HW   = 2048 * 2048;   // pixels
static constexpr int NQ   = HW / 4;        // float4 / int4 quads
static constexpr int NBLK = 512;           // 2 blocks per CU exactly
static constexpr int NTHR = 1024;          // 16 waves per block
static constexpr int QPT  = NQ / (NBLK * NTHR);  // = 2 quads (8 pixels) per thread

// d_ws layout (SoA planes, each NBLK uint4):
//   planeP[NBLK]: per-block p_sum  (argmax==c) for classes 0..3
//   planeT[NBLK]: per-block t_sum  (true==c)
//   planeI[NBLK]: per-block inter  (argmax==c && true==c)

__global__ __launch_bounds__(NTHR) void count_kernel(const float* __restrict__ pred,
                                                     const int* __restrict__ lbl,
                                                     uint4* __restrict__ planeP,
                                                     uint4* __restrict__ planeT,
                                                     uint4* __restrict__ planeI) {
    const float4* __restrict__ p0 = (const float4*)(pred);
    const float4* __restrict__ p1 = (const float4*)(pred + (size_t)HW);
    const float4* __restrict__ p2 = (const float4*)(pred + (size_t)2 * HW);
    const float4* __restrict__ p3 = (const float4*)(pred + (size_t)3 * HW);
    const int4*   __restrict__ tl = (const int4*)(lbl);

    // byte-packed per-thread counters: 8-bit lane per class (max 8 pixels/thread)
    unsigned int pc = 0u, tc = 0u, ic = 0u;

    const int base = blockIdx.x * NTHR + threadIdx.x;
#pragma unroll
    for (int q = 0; q < QPT; ++q) {
        const int i = base + q * (NBLK * NTHR);
        float4 a = p0[i];
        float4 b = p1[i];
        float4 c = p2[i];
        float4 d = p3[i];
        int4   t = tl[i];

        float a_[4] = {a.x, a.y, a.z, a.w};
        float b_[4] = {b.x, b.y, b.z, b.w};
        float c_[4] = {c.x, c.y, c.z, c.w};
        float d_[4] = {d.x, d.y, d.z, d.w};
        int   t_[4] = {t.x, t.y, t.z, t.w};

#pragma unroll
        for (int j = 0; j < 4; ++j) {
            // jnp.argmax tie-break: first (lowest) index among maxima -> strict '>'
            float best = a_[j];
            int   pi   = 0;
            if (b_[j] > best) { best = b_[j]; pi = 1; }
            if (c_[j] > best) { best = c_[j]; pi = 2; }
            if (d_[j] > best) { best = d_[j]; pi = 3; }
            int tj = t_[j];
            pc += 1u << (pi * 8);
            tc += 1u << (tj * 8);
            ic += (pi == tj) ? (1u << (pi * 8)) : 0u;
        }
    }

    // widen 8-bit lanes -> two u32 with 16-bit lanes (classes {0,2} in lo, {1,3} in hi)
    unsigned int plo = pc & 0x00FF00FFu, phi = (pc >> 8) & 0x00FF00FFu;
    unsigned int tlo = tc & 0x00FF00FFu, thi = (tc >> 8) & 0x00FF00FFu;
    unsigned int ilo = ic & 0x00FF00FFu, ihi = (ic >> 8) & 0x00FF00FFu;

    // wave-64 reduction (16-bit lanes: max 64*8=512 per lane, no overflow)
#pragma unroll
    for (int off = 32; off > 0; off >>= 1) {
        plo += __shfl_down(plo, off);
        phi += __shfl_down(phi, off);
        tlo += __shfl_down(tlo, off);
        thi += __shfl_down(thi, off);
        ilo += __shfl_down(ilo, off);
        ihi += __shfl_down(ihi, off);
    }

    __shared__ unsigned int red[NTHR / 64][6];
    int wave = threadIdx.x >> 6;
    int lane = threadIdx.x & 63;
    if (lane == 0) {
        red[wave][0] = plo; red[wave][1] = phi;
        red[wave][2] = tlo; red[wave][3] = thi;
        red[wave][4] = ilo; red[wave][5] = ihi;
    }
    __syncthreads();

    // cross-wave reduce: 16 partial rows x 6 values -> lane k of wave 0 sums value k
    if (threadIdx.x < 64) {
        // each of the first 6 lanes... simpler: thread 0 does 16x6 adds from LDS (fast)
    }
    if (threadIdx.x == 0) {
        unsigned int s[6];
#pragma unroll
        for (int k = 0; k < 6; ++k) {
            unsigned int acc = 0;
#pragma unroll
            for (int w = 0; w < NTHR / 64; ++w) acc += red[w][k];
            s[k] = acc;  // 16-bit lanes: max 16*512 = 8192, no overflow
        }
        // lo16 = class{0 or 1}, hi16 = class{2 or 3}
        planeP[blockIdx.x] = make_uint4(s[0] & 0xFFFFu, s[1] & 0xFFFFu, s[0] >> 16, s[1] >> 16);
        planeT[blockIdx.x] = make_uint4(s[2] & 0xFFFFu, s[3] & 0xFFFFu, s[2] >> 16, s[3] >> 16);
        planeI[blockIdx.x] = make_uint4(s[4] & 0xFFFFu, s[5] & 0xFFFFu, s[4] >> 16, s[5] >> 16);
    }
}

__global__ __launch_bounds__(NBLK) void finalize_kernel(const uint4* __restrict__ planeP,
                                                        const uint4* __restrict__ planeT,
                                                        const uint4* __restrict__ planeI,
                                                        float* __restrict__ out) {
    unsigned int s[12];
#pragma unroll
    for (int k = 0; k < 12; ++k) s[k] = 0u;

    // one row per thread, fully coalesced SoA reads
    {
        const int b = threadIdx.x;
        uint4 r0 = planeP[b], r1 = planeT[b], r2 = planeI[b];
        s[0] += r0.x; s[1] += r0.y; s[2]  += r0.z; s[3]  += r0.w;
        s[4] += r1.x; s[5] += r1.y; s[6]  += r1.z; s[7]  += r1.w;
        s[8] += r2.x; s[9] += r2.y; s[10] += r2.z; s[11] += r2.w;
    }

    // wave reduce each of the 12 sums
#pragma unroll
    for (int off = 32; off > 0; off >>= 1) {
#pragma unroll
        for (int k = 0; k < 12; ++k) s[k] += __shfl_down(s[k], off);
    }

    __shared__ unsigned int red[NBLK / 64][12];
    int wave = threadIdx.x >> 6;
    int lane = threadIdx.x & 63;
    if (lane == 0) {
#pragma unroll
        for (int k = 0; k < 12; ++k) red[wave][k] = s[k];
    }
    __syncthreads();

    if (threadIdx.x == 0) {
        unsigned int tot[12];
#pragma unroll
        for (int k = 0; k < 12; ++k) {
            unsigned int acc = 0;
#pragma unroll
            for (int w = 0; w < NBLK / 64; ++w) acc += red[w][k];
            tot[k] = acc;
        }
        float p[4], t[4], in[4];
        float sp = 0.f, st = 0.f;
#pragma unroll
        for (int c = 0; c < 4; ++c) {
            p[c]  = (float)tot[c];
            t[c]  = (float)tot[4 + c];
            in[c] = (float)tot[8 + c];
            sp += p[c];
            st += t[c];
        }
        const float S = 1e-5f;
        float total = sp + st;  // == p1h.sum() + t1h.sum()
        float dsum = 0.f, isum = 0.f;
        int npres = 0;
#pragma unroll
        for (int c = 0; c < 4; ++c) {
            if (tot[4 + c] > 0u) {  // class present in `true`
                ++npres;
                dsum += 1.0f - (2.0f * in[c] + S) / (p[c] + t[c] + S);
                isum += 1.0f - (in[c] + S) / (total + S - in[c]);
            }
        }
        float n = (float)(npres > 0 ? npres : 1);
        out[0] = dsum / n + isum / n;
    }
}

extern "C" void kernel_launch(void* const* d_in, const int* in_sizes, int n_in,
                              void* d_out, int out_size, void* d_ws, size_t ws_size,
                              hipStream_t stream) {
    const float* pred = (const float*)d_in[0];
    const int*   lbl  = (const int*)d_in[1];
    float*       out  = (float*)d_out;
    uint4* planeP = (uint4*)d_ws;            // NBLK uint4 = 8 KB
    uint4* planeT = planeP + NBLK;           // 8 KB
    uint4* planeI = planeT + NBLK;           // 8 KB

    count_kernel<<<NBLK, NTHR, 0, stream>>>(pred, lbl, planeP, planeT, planeI);
    finalize_kernel<<<1, NBLK, 0, stream>>>(planeP, planeT, planeI, out);
}

// Round 7
// 23.332 us; speedup vs baseline: 1.1172x; 1.0275x over previous
//
#include <hip/hip_runtime.h>

// Problem constants: pred [1,4,2048,2048] fp32, true [2048,2048] int32 (labels 0..3)
static constexpr int HW   = 2048 * 2048;   // pixels
static constexpr int NQ   = HW / 4;        // float4 / int4 quads
static constexpr int NBLK = 512;           // 2 blocks per CU exactly
static constexpr int NTHR = 1024;          // 16 waves per block
static constexpr int QPT  = NQ / (NBLK * NTHR);  // = 2 quads (8 pixels) per thread

// d_ws layout (SoA planes, each NBLK uint4):
//   planeP[NBLK]: per-block p_sum  (argmax==c) for classes 0..3
//   planeT[NBLK]: per-block t_sum  (true==c)
//   planeI[NBLK]: per-block inter  (argmax==c && true==c)

__global__ __launch_bounds__(NTHR) void count_kernel(const float* __restrict__ pred,
                                                     const int* __restrict__ lbl,
                                                     uint4* __restrict__ planeP,
                                                     uint4* __restrict__ planeT,
                                                     uint4* __restrict__ planeI) {
    const float4* __restrict__ p0 = (const float4*)(pred);
    const float4* __restrict__ p1 = (const float4*)(pred + (size_t)HW);
    const float4* __restrict__ p2 = (const float4*)(pred + (size_t)2 * HW);
    const float4* __restrict__ p3 = (const float4*)(pred + (size_t)3 * HW);
    const int4*   __restrict__ tl = (const int4*)(lbl);

    // byte-packed per-thread counters: 8-bit lane per class (max 8 pixels/thread)
    unsigned int pc = 0u, tc = 0u, ic = 0u;

    // consecutive 32B per thread per stream: thread handles quads {2*base, 2*base+1}
    const int base = blockIdx.x * NTHR + threadIdx.x;
#pragma unroll
    for (int q = 0; q < QPT; ++q) {
        const int i = 2 * base + q;
        float4 a = p0[i];
        float4 b = p1[i];
        float4 c = p2[i];
        float4 d = p3[i];
        int4   t = tl[i];

        float a_[4] = {a.x, a.y, a.z, a.w};
        float b_[4] = {b.x, b.y, b.z, b.w};
        float c_[4] = {c.x, c.y, c.z, c.w};
        float d_[4] = {d.x, d.y, d.z, d.w};
        int   t_[4] = {t.x, t.y, t.z, t.w};

#pragma unroll
        for (int j = 0; j < 4; ++j) {
            // jnp.argmax tie-break: first (lowest) index among maxima -> strict '>'
            float best = a_[j];
            int   pi   = 0;
            if (b_[j] > best) { best = b_[j]; pi = 1; }
            if (c_[j] > best) { best = c_[j]; pi = 2; }
            if (d_[j] > best) { best = d_[j]; pi = 3; }
            int tj = t_[j];
            pc += 1u << (pi * 8);
            tc += 1u << (tj * 8);
            ic += (pi == tj) ? (1u << (pi * 8)) : 0u;
        }
    }

    // widen 8-bit lanes -> two u32 with 16-bit lanes (classes {0,2} in lo, {1,3} in hi)
    unsigned int plo = pc & 0x00FF00FFu, phi = (pc >> 8) & 0x00FF00FFu;
    unsigned int tlo = tc & 0x00FF00FFu, thi = (tc >> 8) & 0x00FF00FFu;
    unsigned int ilo = ic & 0x00FF00FFu, ihi = (ic >> 8) & 0x00FF00FFu;

    // wave-64 reduction (16-bit lanes: max 64*8=512 per lane, no overflow)
#pragma unroll
    for (int off = 32; off > 0; off >>= 1) {
        plo += __shfl_down(plo, off);
        phi += __shfl_down(phi, off);
        tlo += __shfl_down(tlo, off);
        thi += __shfl_down(thi, off);
        ilo += __shfl_down(ilo, off);
        ihi += __shfl_down(ihi, off);
    }

    __shared__ unsigned int red[NTHR / 64][6];
    int wave = threadIdx.x >> 6;
    int lane = threadIdx.x & 63;
    if (lane == 0) {
        red[wave][0] = plo; red[wave][1] = phi;
        red[wave][2] = tlo; red[wave][3] = thi;
        red[wave][4] = ilo; red[wave][5] = ihi;
    }
    __syncthreads();

    if (threadIdx.x == 0) {
        unsigned int s[6];
#pragma unroll
        for (int k = 0; k < 6; ++k) {
            unsigned int acc = 0;
#pragma unroll
            for (int w = 0; w < NTHR / 64; ++w) acc += red[w][k];
            s[k] = acc;  // 16-bit lanes: max 16*512 = 8192, no overflow
        }
        // lo16 = class{0 or 1}, hi16 = class{2 or 3}
        planeP[blockIdx.x] = make_uint4(s[0] & 0xFFFFu, s[1] & 0xFFFFu, s[0] >> 16, s[1] >> 16);
        planeT[blockIdx.x] = make_uint4(s[2] & 0xFFFFu, s[3] & 0xFFFFu, s[2] >> 16, s[3] >> 16);
        planeI[blockIdx.x] = make_uint4(s[4] & 0xFFFFu, s[5] & 0xFFFFu, s[4] >> 16, s[5] >> 16);
    }
}

__global__ __launch_bounds__(NBLK) void finalize_kernel(const uint4* __restrict__ planeP,
                                                        const uint4* __restrict__ planeT,
                                                        const uint4* __restrict__ planeI,
                                                        float* __restrict__ out) {
    unsigned int s[12];
#pragma unroll
    for (int k = 0; k < 12; ++k) s[k] = 0u;

    // one row per thread, fully coalesced SoA reads
    {
        const int b = threadIdx.x;
        uint4 r0 = planeP[b], r1 = planeT[b], r2 = planeI[b];
        s[0] += r0.x; s[1] += r0.y; s[2]  += r0.z; s[3]  += r0.w;
        s[4] += r1.x; s[5] += r1.y; s[6]  += r1.z; s[7]  += r1.w;
        s[8] += r2.x; s[9] += r2.y; s[10] += r2.z; s[11] += r2.w;
    }

    // wave reduce each of the 12 sums
#pragma unroll
    for (int off = 32; off > 0; off >>= 1) {
#pragma unroll
        for (int k = 0; k < 12; ++k) s[k] += __shfl_down(s[k], off);
    }

    __shared__ unsigned int red[NBLK / 64][12];
    int wave = threadIdx.x >> 6;
    int lane = threadIdx.x & 63;
    if (lane == 0) {
#pragma unroll
        for (int k = 0; k < 12; ++k) red[wave][k] = s[k];
    }
    __syncthreads();

    if (threadIdx.x == 0) {
        unsigned int tot[12];
#pragma unroll
        for (int k = 0; k < 12; ++k) {
            unsigned int acc = 0;
#pragma unroll
            for (int w = 0; w < NBLK / 64; ++w) acc += red[w][k];
            tot[k] = acc;
        }
        float p[4], t[4], in[4];
        float sp = 0.f, st = 0.f;
#pragma unroll
        for (int c = 0; c < 4; ++c) {
            p[c]  = (float)tot[c];
            t[c]  = (float)tot[4 + c];
            in[c] = (float)tot[8 + c];
            sp += p[c];
            st += t[c];
        }
        const float S = 1e-5f;
        float total = sp + st;  // == p1h.sum() + t1h.sum()
        float dsum = 0.f, isum = 0.f;
        int npres = 0;
#pragma unroll
        for (int c = 0; c < 4; ++c) {
            if (tot[4 + c] > 0u) {  // class present in `true`
                ++npres;
                dsum += 1.0f - (2.0f * in[c] + S) / (p[c] + t[c] + S);
                isum += 1.0f - (in[c] + S) / (total + S - in[c]);
            }
        }
        float n = (float)(npres > 0 ? npres : 1);
        out[0] = dsum / n + isum / n;
    }
}

extern "C" void kernel_launch(void* const* d_in, const int* in_sizes, int n_in,
                              void* d_out, int out_size, void* d_ws, size_t ws_size,
                              hipStream_t stream) {
    const float* pred = (const float*)d_in[0];
    const int*   lbl  = (const int*)d_in[1];
    float*       out  = (float*)d_out;
    uint4* planeP = (uint4*)d_ws;            // NBLK uint4 = 8 KB
    uint4* planeT = planeP + NBLK;           // 8 KB
    uint4* planeI = planeT + NBLK;           // 8 KB

    count_kernel<<<NBLK, NTHR, 0, stream>>>(pred, lbl, planeP, planeT, planeI);
    finalize_kernel<<<1, NBLK, 0, stream>>>(planeP, planeT, planeI, out);
}